// Round 1
// baseline (194.218 us; speedup 1.0000x reference)
//
#include <hip/hip_runtime.h>

typedef __attribute__((ext_vector_type(8))) __bf16 bf16x8;
typedef __attribute__((ext_vector_type(4))) float f32x4;

constexpr int Bn = 8192, Nn = 256, M1n = 128, M2n = 64, Mn = 192, ITERS = 30;
constexpr float TAUc = 0.05f, SIGc = 0.05f;

__device__ __forceinline__ ushort f2bf(float f) {
  unsigned u = __builtin_bit_cast(unsigned, f);
  u = (u + 0x7FFFu + ((u >> 16) & 1u)) >> 16;
  return (ushort)u;
}

// Build bf16 copies of A = [A1;A2] in both orientations:
// Arm[m][n] (192x256 row-major), AT[n][m] (256x192 row-major).
__global__ void prep_kernel(const float* __restrict__ A1, const float* __restrict__ A2,
                            ushort* __restrict__ Arm, ushort* __restrict__ AT) {
  int i = blockIdx.x * 256 + threadIdx.x;
  if (i >= Mn * Nn) return;
  int m = i / Nn, n = i % Nn;
  float v = (m < M1n) ? A1[m * Nn + n] : A2[(m - M1n) * Nn + n];
  ushort b = f2bf(v);
  Arm[m * Nn + n] = b;
  AT[n * Mn + m] = b;
}

__global__ __launch_bounds__(128) void pdhg_kernel(
    const float* __restrict__ x0, const float* __restrict__ y10,
    const float* __restrict__ y20, const float* __restrict__ z,
    const float* __restrict__ c, const ushort* __restrict__ Arm,
    const ushort* __restrict__ AT, float* __restrict__ out) {
  // padded LDS rows: stride 264 (528B) and 200 (400B) -> uniform bank-group spread
  __shared__ __align__(16) ushort xb_lds[16][264];
  __shared__ __align__(16) ushort y_lds[16][200];

  const int lane = threadIdx.x & 63;
  const int wave = threadIdx.x >> 6;  // 0 or 1: column-split of the band
  const int fr = lane & 15;           // fragment row (A-op) / col (B-op, C/D)
  const int kg = lane >> 4;           // k-group 0..3
  const int row0 = blockIdx.x * 16;   // this block's 16-row band

  float x[8][4];   // per-wave n-half of x state (8 n-tiles x 4 rows)
  float y[6][4];   // per-wave m-half of y state (6 m-tiles)
  float zv[6][4];
  float cv[8];

  // ---- init: load x0 (also write initial xbar = x0 to LDS), y0, z, c
#pragma unroll
  for (int nt = 0; nt < 8; ++nt) {
    int n = (wave * 8 + nt) * 16 + fr;
    cv[nt] = c[n];
#pragma unroll
    for (int g = 0; g < 4; ++g) {
      float v = x0[(row0 + kg * 4 + g) * Nn + n];
      x[nt][g] = v;
      xb_lds[kg * 4 + g][n] = f2bf(v);
    }
  }
#pragma unroll
  for (int mt = 0; mt < 6; ++mt) {
    int m = (wave * 6 + mt) * 16 + fr;
#pragma unroll
    for (int g = 0; g < 4; ++g) {
      int r = row0 + kg * 4 + g;
      zv[mt][g] = z[r * Mn + m];
      y[mt][g] = (m < M1n) ? y10[r * M1n + m] : y20[r * M2n + (m - M1n)];
    }
  }
  __syncthreads();

  // global B-fragment bases (loop-invariant; L2-resident bf16 copies of A)
  const ushort* armB = Arm + (wave * 96 + fr) * Nn + kg * 8;   // Arm[m][k]
  const ushort* atB  = AT  + (wave * 128 + fr) * Mn + kg * 8;  // AT[n][k=m]

  for (int it = 0; it < ITERS; ++it) {
    // ---- xbar A-fragments from LDS (full K=256, both waves' halves)
    bf16x8 fx[8];
#pragma unroll
    for (int kf = 0; kf < 8; ++kf)
      fx[kf] = *reinterpret_cast<const bf16x8*>(&xb_lds[fr][kf * 32 + kg * 8]);

    // ---- GEMM-1: S = xbar @ A^T  (this wave's 6 m-tiles)
    f32x4 acc[6];
#pragma unroll
    for (int mt = 0; mt < 6; ++mt) acc[mt] = f32x4{0.f, 0.f, 0.f, 0.f};
#pragma unroll
    for (int kf = 0; kf < 8; ++kf) {
#pragma unroll
      for (int mt = 0; mt < 6; ++mt) {
        bf16x8 bf = *reinterpret_cast<const bf16x8*>(armB + mt * 16 * Nn + kf * 32);
        acc[mt] = __builtin_amdgcn_mfma_f32_16x16x32_bf16(fx[kf], bf, acc[mt], 0, 0, 0);
      }
    }

    // ---- y update (f32 state), write bf16 Y to LDS
#pragma unroll
    for (int mt = 0; mt < 6; ++mt) {
      int m = (wave * 6 + mt) * 16 + fr;
      const bool isy1 = (wave * 6 + mt) < 8;  // m-tile < 8 -> m < 128 -> relu
#pragma unroll
      for (int g = 0; g < 4; ++g) {
        float s = y[mt][g] + SIGc * (acc[mt][g] - zv[mt][g]);
        if (isy1) s = fmaxf(s, 0.f);
        y[mt][g] = s;
        y_lds[kg * 4 + g][m] = f2bf(s);
      }
    }
    __syncthreads();

    // ---- y A-fragments from LDS (full K=192)
    bf16x8 fy[6];
#pragma unroll
    for (int kf = 0; kf < 6; ++kf)
      fy[kf] = *reinterpret_cast<const bf16x8*>(&y_lds[fr][kf * 32 + kg * 8]);

    // ---- GEMM-3: G = y @ A  (this wave's 8 n-tiles)
    f32x4 acc2[8];
#pragma unroll
    for (int nt = 0; nt < 8; ++nt) acc2[nt] = f32x4{0.f, 0.f, 0.f, 0.f};
#pragma unroll
    for (int kf = 0; kf < 6; ++kf) {
#pragma unroll
      for (int nt = 0; nt < 8; ++nt) {
        bf16x8 bf = *reinterpret_cast<const bf16x8*>(atB + nt * 16 * Mn + kf * 32);
        acc2[nt] = __builtin_amdgcn_mfma_f32_16x16x32_bf16(fy[kf], bf, acc2[nt], 0, 0, 0);
      }
    }

    // ---- x update (f32 state), write bf16 xbar to LDS
    const bool notlast = (it != ITERS - 1);
#pragma unroll
    for (int nt = 0; nt < 8; ++nt) {
      int n = (wave * 8 + nt) * 16 + fr;
#pragma unroll
      for (int g = 0; g < 4; ++g) {
        float grad = cv[nt] + acc2[nt][g];
        float xn = fmaxf(x[nt][g] - TAUc * grad, 0.f);
        float xb = 2.f * xn - x[nt][g];  // theta = 1
        x[nt][g] = xn;
        if (notlast) xb_lds[kg * 4 + g][n] = f2bf(xb);
      }
    }
    __syncthreads();
  }

  // ---- store outputs: x (B x 256), y1 (B x 128), y2 (B x 64), all f32
  float* ox = out;
  float* oy1 = out + Bn * Nn;
  float* oy2 = oy1 + Bn * M1n;
#pragma unroll
  for (int nt = 0; nt < 8; ++nt) {
    int n = (wave * 8 + nt) * 16 + fr;
#pragma unroll
    for (int g = 0; g < 4; ++g)
      ox[(row0 + kg * 4 + g) * Nn + n] = x[nt][g];
  }
#pragma unroll
  for (int mt = 0; mt < 6; ++mt) {
    int m = (wave * 6 + mt) * 16 + fr;
#pragma unroll
    for (int g = 0; g < 4; ++g) {
      int r = row0 + kg * 4 + g;
      if (m < M1n) oy1[r * M1n + m] = y[mt][g];
      else         oy2[r * M2n + (m - M1n)] = y[mt][g];
    }
  }
}

extern "C" void kernel_launch(void* const* d_in, const int* in_sizes, int n_in,
                              void* d_out, int out_size, void* d_ws, size_t ws_size,
                              hipStream_t stream) {
  const float* x0  = (const float*)d_in[0];
  const float* y10 = (const float*)d_in[1];
  const float* y20 = (const float*)d_in[2];
  const float* z   = (const float*)d_in[3];
  const float* c   = (const float*)d_in[4];
  const float* A1  = (const float*)d_in[5];
  const float* A2  = (const float*)d_in[6];

  ushort* Arm = (ushort*)d_ws;          // 192*256 bf16
  ushort* AT  = Arm + Mn * Nn;          // 256*192 bf16

  prep_kernel<<<(Mn * Nn + 255) / 256, 256, 0, stream>>>(A1, A2, Arm, AT);
  pdhg_kernel<<<Bn / 16, 128, 0, stream>>>(x0, y10, y20, z, c, Arm, AT, (float*)d_out);
}

// Round 2
// 79.951 us; speedup vs baseline: 2.4292x; 2.4292x over previous
//
#include <hip/hip_runtime.h>

typedef __attribute__((ext_vector_type(8))) __bf16 bf16x8;
typedef __attribute__((ext_vector_type(4))) float f32x4;

constexpr int Bn = 8192, Nn = 256, M1n = 128, M2n = 64, Mn = 192, ITERS = 30;
constexpr float TAUc = 0.05f, SIGc = 0.05f;

__device__ __forceinline__ ushort f2bf(float f) {
  unsigned u = __builtin_bit_cast(unsigned, f);
  u = (u + 0x7FFFu + ((u >> 16) & 1u)) >> 16;
  return (ushort)u;
}

// Build bf16 copies of A = [A1;A2] in both orientations:
// Arm[m][n] (192x256 row-major), AT[n][m] (256x192 row-major).
__global__ void prep_kernel(const float* __restrict__ A1, const float* __restrict__ A2,
                            ushort* __restrict__ Arm, ushort* __restrict__ AT) {
  int i = blockIdx.x * 256 + threadIdx.x;
  if (i >= Mn * Nn) return;
  int m = i / Nn, n = i % Nn;
  float v = (m < M1n) ? A1[m * Nn + n] : A2[(m - M1n) * Nn + n];
  ushort b = f2bf(v);
  Arm[m * Nn + n] = b;
  AT[n * Mn + m] = b;
}

// 8 waves per block, one 16-row band per block.
// Wave w owns: GEMM-1 m-tiles {w} (+ {8+w} if w<4); GEMM-3 n-tiles {2w, 2w+1}.
// All A fragments live in registers across the 30 iterations (112 VGPRs).
__global__ __launch_bounds__(512, 2) void pdhg_kernel(
    const float* __restrict__ x0, const float* __restrict__ y10,
    const float* __restrict__ y20, const float* __restrict__ z,
    const float* __restrict__ c, const ushort* __restrict__ Arm,
    const ushort* __restrict__ AT, float* __restrict__ out) {
  __shared__ __align__(16) ushort xb_lds[16][264];  // xbar band, padded stride
  __shared__ __align__(16) ushort y_lds[16][200];   // y band, padded stride

  const int lane = threadIdx.x & 63;
  const int w = threadIdx.x >> 6;     // wave 0..7
  const int fr = lane & 15;           // fragment row (A-op) / col (B-op, C/D)
  const int kg = lane >> 4;           // k-group 0..3
  const int row0 = blockIdx.x * 16;   // this block's 16-row band

  const int nt0 = 2 * w;              // n-tiles nt0, nt0+1
  const int mt0 = w;                  // primary m-tile (0..7 -> y1, relu)
  const bool two_m = (w < 4);
  const int mt1 = two_m ? (8 + w) : w;  // secondary m-tile (8..11 -> y2); clamped if unused
  const int m0 = mt0 * 16 + fr;
  const int m1 = mt1 * 16 + fr;

  float x[2][4], cv[2];
  float y0s[4], z0s[4], y1s[4], z1s[4];

  // ---- init x state + initial xbar = x0 into LDS
#pragma unroll
  for (int t = 0; t < 2; ++t) {
    int n = (nt0 + t) * 16 + fr;
    cv[t] = c[n];
#pragma unroll
    for (int g = 0; g < 4; ++g) {
      float v = x0[(row0 + kg * 4 + g) * Nn + n];
      x[t][g] = v;
      xb_lds[kg * 4 + g][n] = f2bf(v);
    }
  }
  // ---- init y, z state
#pragma unroll
  for (int g = 0; g < 4; ++g) {
    int r = row0 + kg * 4 + g;
    z0s[g] = z[r * Mn + m0];
    y0s[g] = y10[r * M1n + m0];
    z1s[g] = z[r * Mn + m1];
    y1s[g] = two_m ? y20[r * M2n + (m1 - M1n)] : 0.f;
  }

  // ---- preload loop-invariant A fragments into registers
  bf16x8 armF0[8], armF1[8], atF[2][6];
#pragma unroll
  for (int kf = 0; kf < 8; ++kf) {
    armF0[kf] = *reinterpret_cast<const bf16x8*>(&Arm[m0 * Nn + kf * 32 + kg * 8]);
    armF1[kf] = *reinterpret_cast<const bf16x8*>(&Arm[m1 * Nn + kf * 32 + kg * 8]);
  }
#pragma unroll
  for (int t = 0; t < 2; ++t)
#pragma unroll
    for (int kf = 0; kf < 6; ++kf)
      atF[t][kf] = *reinterpret_cast<const bf16x8*>(&AT[((nt0 + t) * 16 + fr) * Mn + kf * 32 + kg * 8]);

  __syncthreads();

  for (int it = 0; it < ITERS; ++it) {
    // ---- xbar A-fragments from LDS (full K=256)
    bf16x8 fx[8];
#pragma unroll
    for (int kf = 0; kf < 8; ++kf)
      fx[kf] = *reinterpret_cast<const bf16x8*>(&xb_lds[fr][kf * 32 + kg * 8]);

    // ---- GEMM-1: S = xbar @ A^T  (1 or 2 m-tiles, A resident in regs)
    f32x4 a0 = {0.f, 0.f, 0.f, 0.f}, a1 = {0.f, 0.f, 0.f, 0.f};
    if (two_m) {
#pragma unroll
      for (int kf = 0; kf < 8; ++kf) {
        a0 = __builtin_amdgcn_mfma_f32_16x16x32_bf16(fx[kf], armF0[kf], a0, 0, 0, 0);
        a1 = __builtin_amdgcn_mfma_f32_16x16x32_bf16(fx[kf], armF1[kf], a1, 0, 0, 0);
      }
    } else {
#pragma unroll
      for (int kf = 0; kf < 8; ++kf)
        a0 = __builtin_amdgcn_mfma_f32_16x16x32_bf16(fx[kf], armF0[kf], a0, 0, 0, 0);
    }

    // ---- y update (f32 state), write bf16 Y band to LDS
#pragma unroll
    for (int g = 0; g < 4; ++g) {
      float s = fmaxf(y0s[g] + SIGc * (a0[g] - z0s[g]), 0.f);  // tiles 0..7 -> relu
      y0s[g] = s;
      y_lds[kg * 4 + g][m0] = f2bf(s);
    }
    if (two_m) {
#pragma unroll
      for (int g = 0; g < 4; ++g) {
        float s = y1s[g] + SIGc * (a1[g] - z1s[g]);  // tiles 8..11 -> linear
        y1s[g] = s;
        y_lds[kg * 4 + g][m1] = f2bf(s);
      }
    }
    __syncthreads();

    // ---- y A-fragments from LDS (full K=192)
    bf16x8 fy[6];
#pragma unroll
    for (int kf = 0; kf < 6; ++kf)
      fy[kf] = *reinterpret_cast<const bf16x8*>(&y_lds[fr][kf * 32 + kg * 8]);

    // ---- GEMM-3: G = y @ A  (2 n-tiles, A^T resident in regs)
    f32x4 b0 = {0.f, 0.f, 0.f, 0.f}, b1 = {0.f, 0.f, 0.f, 0.f};
#pragma unroll
    for (int kf = 0; kf < 6; ++kf) {
      b0 = __builtin_amdgcn_mfma_f32_16x16x32_bf16(fy[kf], atF[0][kf], b0, 0, 0, 0);
      b1 = __builtin_amdgcn_mfma_f32_16x16x32_bf16(fy[kf], atF[1][kf], b1, 0, 0, 0);
    }

    // ---- x update (f32 state), write bf16 xbar to LDS
    const bool notlast = (it != ITERS - 1);
#pragma unroll
    for (int t = 0; t < 2; ++t) {
      int n = (nt0 + t) * 16 + fr;
      f32x4 bb = t ? b1 : b0;
#pragma unroll
      for (int g = 0; g < 4; ++g) {
        float grad = cv[t] + bb[g];
        float xn = fmaxf(x[t][g] - TAUc * grad, 0.f);
        float xb = 2.f * xn - x[t][g];  // theta = 1
        x[t][g] = xn;
        if (notlast) xb_lds[kg * 4 + g][n] = f2bf(xb);
      }
    }
    __syncthreads();
  }

  // ---- store outputs: x (B x 256), y1 (B x 128), y2 (B x 64), all f32
  float* ox = out;
  float* oy1 = out + Bn * Nn;
  float* oy2 = oy1 + Bn * M1n;
#pragma unroll
  for (int t = 0; t < 2; ++t) {
    int n = (nt0 + t) * 16 + fr;
#pragma unroll
    for (int g = 0; g < 4; ++g)
      ox[(row0 + kg * 4 + g) * Nn + n] = x[t][g];
  }
#pragma unroll
  for (int g = 0; g < 4; ++g) {
    int r = row0 + kg * 4 + g;
    oy1[r * M1n + m0] = y0s[g];
  }
  if (two_m) {
#pragma unroll
    for (int g = 0; g < 4; ++g) {
      int r = row0 + kg * 4 + g;
      oy2[r * M2n + (m1 - M1n)] = y1s[g];
    }
  }
}

extern "C" void kernel_launch(void* const* d_in, const int* in_sizes, int n_in,
                              void* d_out, int out_size, void* d_ws, size_t ws_size,
                              hipStream_t stream) {
  const float* x0  = (const float*)d_in[0];
  const float* y10 = (const float*)d_in[1];
  const float* y20 = (const float*)d_in[2];
  const float* z   = (const float*)d_in[3];
  const float* c   = (const float*)d_in[4];
  const float* A1  = (const float*)d_in[5];
  const float* A2  = (const float*)d_in[6];

  ushort* Arm = (ushort*)d_ws;          // 192*256 bf16
  ushort* AT  = Arm + Mn * Nn;          // 256*192 bf16

  prep_kernel<<<(Mn * Nn + 255) / 256, 256, 0, stream>>>(A1, A2, Arm, AT);
  pdhg_kernel<<<Bn / 16, 512, 0, stream>>>(x0, y10, y20, z, c, Arm, AT, (float*)d_out);
}